// Round 1
// 4617.802 us; speedup vs baseline: 1.0167x; 1.0167x over previous
//
#include <hip/hip_runtime.h>
#include <math.h>

#define N_NODES 200000
#define H_CH    128
#define GRP     64          // channel group width (2 groups of 64)
#define NNZ_E   3200000
#define K_DEG   15

// bucketed CSR build parameters
#define EPB     4096        // edges per block in bucket pass A
#define BSHIFT  9           // 512 rows per bucket
#define NBUCK   391         // ceil(200000 / 512)
#define BCAP    9216        // per-bucket staging capacity (mean 8192, +11 sigma)

// ---------- softmax over 16 logits ----------
__global__ void softmax_k(const float* __restrict__ logits, float* __restrict__ w) {
    if (threadIdx.x == 0) {
        float m = -1e30f;
        for (int i = 0; i <= K_DEG; ++i) m = fmaxf(m, logits[i]);
        float e[K_DEG + 1];
        float s = 0.f;
        for (int i = 0; i <= K_DEG; ++i) { e[i] = expf(logits[i] - m); s += e[i]; }
        float inv = 1.0f / s;
        for (int i = 0; i <= K_DEG; ++i) w[i] = e[i] * inv;
    }
}

// ---------- bucket pass A: block-local LDS binning by row bucket ----------
// Also folds in the row histogram (replaces hist_k).
// Output: stag[b*BCAP + ...] holds packed (rowlow<<18 | col, val_bits) runs,
// one contiguous run per (block, bucket) -> ~full-line HBM writes.
__global__ __launch_bounds__(256) void bucketA_k(
    const int* __restrict__ row, const int* __restrict__ col,
    const float* __restrict__ vals, int* __restrict__ counts,
    int* __restrict__ gfill, uint2* __restrict__ stag, int nnz) {
    __shared__ int cnt[NBUCK];          // per-block bucket counts, then cursors
    __shared__ int excl[NBUCK];         // exclusive offsets within block
    __shared__ int gbase[NBUCK];        // global append base per bucket
    __shared__ int sm[256];
    __shared__ uint2 sstag[EPB];        // binned edges (packed, val)
    __shared__ unsigned short sb[EPB];  // bucket id per binned slot

    int tid = threadIdx.x;
    int base = blockIdx.x * EPB;

    for (int t = tid; t < NBUCK; t += 256) cnt[t] = 0;
    __syncthreads();

    int r[16], c[16], b[16];
    float v[16];
#pragma unroll
    for (int j = 0; j < 16; ++j) {
        int i = base + j * 256 + tid;
        if (i < nnz) {
            r[j] = row[i]; c[j] = col[i]; v[j] = vals[i];
            b[j] = r[j] >> BSHIFT;
            atomicAdd(&cnt[b[j]], 1);
            atomicAdd(&counts[r[j]], 1);      // fused row histogram
        } else {
            b[j] = -1;
        }
    }
    __syncthreads();

    // exclusive scan of cnt[0..NBUCK) -> excl[]; 2 bins per thread
    {
        int b0 = 2 * tid, b1 = 2 * tid + 1;
        int c0 = (b0 < NBUCK) ? cnt[b0] : 0;
        int c1 = (b1 < NBUCK) ? cnt[b1] : 0;
        int pair = c0 + c1;
        sm[tid] = pair;
        __syncthreads();
        int incl = pair;
        for (int off = 1; off < 256; off <<= 1) {
            int tv = (tid >= off) ? sm[tid - off] : 0;
            __syncthreads();
            incl += tv;
            sm[tid] = incl;
            __syncthreads();
        }
        int pexcl = incl - pair;
        if (b0 < NBUCK) excl[b0] = pexcl;
        if (b1 < NBUCK) excl[b1] = pexcl + c0;
    }
    __syncthreads();

    // reserve global ranges, then convert cnt[] into LDS cursors
    for (int t = tid; t < NBUCK; t += 256) {
        int cb = cnt[t];
        gbase[t] = (cb > 0) ? atomicAdd(&gfill[t], cb) : 0;
    }
    __syncthreads();
    for (int t = tid; t < NBUCK; t += 256) cnt[t] = excl[t];
    __syncthreads();

    // bin edges into LDS by bucket
#pragma unroll
    for (int j = 0; j < 16; ++j) {
        if (b[j] >= 0) {
            int p = atomicAdd(&cnt[b[j]], 1);
            sstag[p] = make_uint2(((unsigned)(r[j] & 511) << 18) | (unsigned)c[j],
                                  __float_as_uint(v[j]));
            sb[p] = (unsigned short)b[j];
        }
    }
    __syncthreads();

    // write LDS-ordered entries: contiguous global run per bucket
    int tot = nnz - base; if (tot > EPB) tot = EPB;
    for (int i = tid; i < tot; i += 256) {
        int bb = sb[i];
        size_t gp = (size_t)bb * BCAP + gbase[bb] + (i - excl[bb]);
        stag[gp] = sstag[i];
    }
}

// ---------- CSR build: hierarchical exclusive scan (tile = 2048) ----------
__global__ void scan1_k(const int* __restrict__ counts, int* __restrict__ out,
                        int* __restrict__ partials, int n) {
    __shared__ int sm[256];
    int tbase = blockIdx.x * 2048 + threadIdx.x * 8;
    int v[8];
    int tsum = 0;
#pragma unroll
    for (int j = 0; j < 8; ++j) {
        int i = tbase + j;
        int c = (i < n) ? counts[i] : 0;
        v[j] = tsum;
        tsum += c;
    }
    sm[threadIdx.x] = tsum;
    __syncthreads();
    int incl = tsum;
    for (int off = 1; off < 256; off <<= 1) {
        int t = (threadIdx.x >= (unsigned)off) ? sm[threadIdx.x - off] : 0;
        __syncthreads();
        incl += t;
        sm[threadIdx.x] = incl;
        __syncthreads();
    }
    int texcl = incl - tsum;
    if (threadIdx.x == 255) partials[blockIdx.x] = incl;
#pragma unroll
    for (int j = 0; j < 8; ++j) {
        int i = tbase + j;
        if (i < n) out[i] = texcl + v[j];
    }
}

__global__ void scan2_k(int* partials, int nb, int* row_ptr, int n, int total) {
    __shared__ int sm[128];
    int v = (threadIdx.x < (unsigned)nb) ? partials[threadIdx.x] : 0;
    sm[threadIdx.x] = v;
    __syncthreads();
    int incl = v;
    for (int off = 1; off < 128; off <<= 1) {
        int t = (threadIdx.x >= (unsigned)off) ? sm[threadIdx.x - off] : 0;
        __syncthreads();
        incl += t;
        sm[threadIdx.x] = incl;
        __syncthreads();
    }
    if (threadIdx.x < (unsigned)nb) partials[threadIdx.x] = incl - v;
    if (threadIdx.x == 0) row_ptr[n] = total;
}

__global__ void scan3_k(int* __restrict__ row_ptr, const int* __restrict__ partials,
                        int* __restrict__ fill, int n) {
    int off = partials[blockIdx.x];
    int tbase = blockIdx.x * 2048 + threadIdx.x * 8;
#pragma unroll
    for (int j = 0; j < 8; ++j) {
        int i = tbase + j;
        if (i < n) {
            int v = row_ptr[i] + off;
            row_ptr[i] = v;
            fill[i] = v;
        }
    }
}

// ---------- bucket pass B: per-bucket scatter to final CSR slots ----------
// One block per bucket: all writes land in a 64 KB csr window -> one L2,
// full-line evictions, write amp ~1.
__global__ __launch_bounds__(256) void bucketB_k(
    const uint2* __restrict__ stag, const int* __restrict__ gfill,
    int* __restrict__ fill, int2* __restrict__ csr) {
    int b = blockIdx.x;
    int n = gfill[b];
    const uint2* s = stag + (size_t)b * BCAP;
    for (int i = threadIdx.x; i < n; i += 256) {
        uint2 e = s[i];
        int rl = (int)(e.x >> 18);
        int cc = (int)(e.x & 0x3FFFF);
        int rr = (b << BSHIFT) | rl;
        int p = atomicAdd(&fill[rr], 1);
        int2 cv;
        cv.x = cc;
        cv.y = (int)e.y;
        csr[p] = cv;
    }
}

// ---------- first fused kernel (per 64-ch group) ----------
// S = spmm(x_g); T1_g = S - x_g (compact);
// out_g = -(w0*x_g + w1*T1_g) + alpha*(x_g - 0.5*S)
__global__ __launch_bounds__(256) void first_k(
    const int* __restrict__ rp, const int2* __restrict__ csr,
    const float* __restrict__ x, float* __restrict__ T1g, float* __restrict__ out,
    const float* __restrict__ w, const float* __restrict__ alpha_p, int goff) {
    int wid = blockIdx.x * 4 + (threadIdx.x >> 6);
    int r = __builtin_amdgcn_readfirstlane(wid);
    if (r >= N_NODES) return;
    int lane = threadIdx.x & 63;
    const float* base = x + goff + lane;      // gather x[col*128 + goff + lane]
    int e0 = rp[r], e1 = rp[r + 1];
    float a0 = 0.f, a1 = 0.f, a2 = 0.f, a3 = 0.f;
    int e = e0;
    for (; e + 4 <= e1; e += 4) {
        int2 cv0 = csr[e], cv1 = csr[e + 1], cv2 = csr[e + 2], cv3 = csr[e + 3];
        a0 = fmaf(__int_as_float(cv0.y), base[(size_t)cv0.x * H_CH], a0);
        a1 = fmaf(__int_as_float(cv1.y), base[(size_t)cv1.x * H_CH], a1);
        a2 = fmaf(__int_as_float(cv2.y), base[(size_t)cv2.x * H_CH], a2);
        a3 = fmaf(__int_as_float(cv3.y), base[(size_t)cv3.x * H_CH], a3);
    }
    for (; e < e1; ++e) {
        int2 cv = csr[e];
        a0 = fmaf(__int_as_float(cv.y), base[(size_t)cv.x * H_CH], a0);
    }
    float s = (a0 + a1) + (a2 + a3);
    size_t idxg = (size_t)r * GRP + lane;
    size_t idxf = (size_t)r * H_CH + goff + lane;
    float xr = x[idxf];
    float w0 = w[0], w1 = w[1], al = alpha_p[0];
    float t1 = s - xr;
    float o = -(w0 * xr + w1 * t1) + al * (xr - 0.5f * s);
    T1g[idxg] = t1;                                   // gather source next step: keep cached
    __builtin_nontemporal_store(o, &out[idxf]);       // streaming: keep out of L3
}

// ---------- Chebyshev step (per 64-ch group) ----------
// y = spmm(Tcur); Tn = 2*(y - Tcur) - Tprev; out -= w[k]*Tn; Tnext = Tn
// nt hints: out RMW and Tprev read are streaming (touched once per k) ->
// keep them from evicting the gather-hot Tcur/Tnext/CSR from L3.
__global__ __launch_bounds__(256) void cheb_k(
    const int* __restrict__ rp, const int2* __restrict__ csr,
    const float* __restrict__ Tcur, const float* TprevBase, int tprevStride,
    float* Tnext, float* __restrict__ out,
    const float* __restrict__ w, int k, int goff) {
    int wid = blockIdx.x * 4 + (threadIdx.x >> 6);
    int r = __builtin_amdgcn_readfirstlane(wid);
    if (r >= N_NODES) return;
    int lane = threadIdx.x & 63;
    const float* base = Tcur + lane;          // gather Tcur[col*64 + lane]
    int e0 = rp[r], e1 = rp[r + 1];
    float a0 = 0.f, a1 = 0.f, a2 = 0.f, a3 = 0.f;
    int e = e0;
    for (; e + 4 <= e1; e += 4) {
        int2 cv0 = csr[e], cv1 = csr[e + 1], cv2 = csr[e + 2], cv3 = csr[e + 3];
        a0 = fmaf(__int_as_float(cv0.y), base[(size_t)cv0.x * GRP], a0);
        a1 = fmaf(__int_as_float(cv1.y), base[(size_t)cv1.x * GRP], a1);
        a2 = fmaf(__int_as_float(cv2.y), base[(size_t)cv2.x * GRP], a2);
        a3 = fmaf(__int_as_float(cv3.y), base[(size_t)cv3.x * GRP], a3);
    }
    for (; e < e1; ++e) {
        int2 cv = csr[e];
        a0 = fmaf(__int_as_float(cv.y), base[(size_t)cv.x * GRP], a0);
    }
    float s = (a0 + a1) + (a2 + a3);
    size_t idxg = (size_t)r * GRP + lane;
    size_t idxf = (size_t)r * H_CH + goff + lane;
    float tc = Tcur[idxg];                                            // gather-hot, cached
    float tp = __builtin_nontemporal_load(&TprevBase[(size_t)r * tprevStride + lane]);
    float wk = w[k];
    float tn = 2.0f * (s - tc) - tp;
    float o = __builtin_nontemporal_load(&out[idxf]);
    o -= wk * tn;
    __builtin_nontemporal_store(o, &out[idxf]);
    Tnext[idxg] = tn;                                                 // next gather source: cached
}

extern "C" void kernel_launch(void* const* d_in, const int* in_sizes, int n_in,
                              void* d_out, int out_size, void* d_ws, size_t ws_size,
                              hipStream_t stream) {
    const float* x      = (const float*)d_in[0];
    const float* vals   = (const float*)d_in[1];
    const float* logits = (const float*)d_in[2];
    const float* alpha  = (const float*)d_in[3];
    const int*   erow   = (const int*)d_in[4];
    const int*   ecol   = (const int*)d_in[5];
    float* out = (float*)d_out;

    const size_t NG = (size_t)N_NODES * GRP;       // per-group state elements
    float* bufA    = (float*)d_ws;                 // N x 64
    float* bufB    = bufA + NG;                    // N x 64
    int2*  csr     = (int2*)(bufB + NG);           // packed col+val, NNZ
    uint2* stag    = (uint2*)(csr + NNZ_E);        // bucket staging, NBUCK*BCAP
    int*   row_ptr = (int*)(stag + (size_t)NBUCK * BCAP);  // N+1
    int*   counts  = row_ptr + (N_NODES + 1);      // N
    int*   gfill   = counts + N_NODES;             // NBUCK (adjacent to counts: one memset)
    int*   fill    = gfill + NBUCK;                // N
    int*   partials= fill + N_NODES;               // 128 entries
    float* w_buf   = (float*)(partials + 128);     // 16 entries

    hipMemsetAsync(counts, 0, (N_NODES + NBUCK) * sizeof(int), stream);
    softmax_k<<<1, 64, 0, stream>>>(logits, w_buf);

    // bucketed CSR build (replaces hist_k + scatter_k)
    int nblkA = (NNZ_E + EPB - 1) / EPB;           // 782
    bucketA_k<<<nblkA, 256, 0, stream>>>(erow, ecol, vals, counts, gfill, stag, NNZ_E);

    const int TILE = 2048;
    int nblk = (N_NODES + TILE - 1) / TILE;        // 98
    scan1_k<<<nblk, 256, 0, stream>>>(counts, row_ptr, partials, N_NODES);
    scan2_k<<<1, 128, 0, stream>>>(partials, nblk, row_ptr, N_NODES, NNZ_E);
    scan3_k<<<nblk, 256, 0, stream>>>(row_ptr, partials, fill, N_NODES);
    bucketB_k<<<NBUCK, 256, 0, stream>>>(stag, gfill, fill, csr);

    int grid = (N_NODES + 3) / 4;                  // 4 rows (waves) per 256-thread block

    for (int g = 0; g < H_CH / GRP; ++g) {
        int goff = g * GRP;
        // T1 (compact) -> bufB; out slice initialized
        first_k<<<grid, 256, 0, stream>>>(row_ptr, csr, x, bufB, out, w_buf, alpha, goff);
        // k = 2: Tcur = T1 (bufB), Tprev = x slice (stride 128), Tnext -> bufA
        cheb_k<<<grid, 256, 0, stream>>>(row_ptr, csr, bufB, x + goff, H_CH, bufA,
                                         out, w_buf, 2, goff);
        // k = 3..15: ping-pong; Tnext aliases Tprev (read-before-write per thread)
        float* Tcur = bufA;
        float* Tprev = bufB;
        for (int k = 3; k <= K_DEG; ++k) {
            cheb_k<<<grid, 256, 0, stream>>>(row_ptr, csr, Tcur, Tprev, GRP, Tprev,
                                             out, w_buf, k, goff);
            float* t = Tcur; Tcur = Tprev; Tprev = t;
        }
    }
}

// Round 2
// 4428.581 us; speedup vs baseline: 1.0601x; 1.0427x over previous
//
#include <hip/hip_runtime.h>
#include <math.h>

#define N_NODES 200000
#define H_CH    128
#define GRP     64          // channel group width (2 groups of 64)
#define NNZ_E   3200000
#define K_DEG   15

// bucketed CSR build parameters
#define EPB     4096        // edges per block in bucket pass A
#define BSHIFT  9           // 512 rows per bucket
#define BROWS   512
#define NBUCK   391         // ceil(200000 / 512)
#define BCAP    9216        // per-bucket staging capacity (mean 8192, +11 sigma)

// ---------- softmax over 16 logits ----------
__global__ void softmax_k(const float* __restrict__ logits, float* __restrict__ w) {
    if (threadIdx.x == 0) {
        float m = -1e30f;
        for (int i = 0; i <= K_DEG; ++i) m = fmaxf(m, logits[i]);
        float e[K_DEG + 1];
        float s = 0.f;
        for (int i = 0; i <= K_DEG; ++i) { e[i] = expf(logits[i] - m); s += e[i]; }
        float inv = 1.0f / s;
        for (int i = 0; i <= K_DEG; ++i) w[i] = e[i] * inv;
    }
}

// ---------- bucket pass A: block-local LDS binning by row bucket ----------
// No global histogram atomics anymore (row counts now derived bucket-locally
// in bucketB). Output: stag[b*BCAP + ...] holds packed (rowlow<<18|col, val)
// runs, one contiguous run per (block, bucket).
__global__ __launch_bounds__(256) void bucketA_k(
    const int* __restrict__ row, const int* __restrict__ col,
    const float* __restrict__ vals,
    int* __restrict__ gfill, uint2* __restrict__ stag, int nnz) {
    __shared__ int cnt[NBUCK];          // per-block bucket counts, then cursors
    __shared__ int excl[NBUCK];         // exclusive offsets within block
    __shared__ int gbase[NBUCK];        // global append base per bucket
    __shared__ int sm[256];
    __shared__ uint2 sstag[EPB];        // binned edges (packed, val)
    __shared__ unsigned short sb[EPB];  // bucket id per binned slot

    int tid = threadIdx.x;
    int base = blockIdx.x * EPB;

    for (int t = tid; t < NBUCK; t += 256) cnt[t] = 0;
    __syncthreads();

    int r[16], c[16], b[16];
    float v[16];
#pragma unroll
    for (int j = 0; j < 16; ++j) {
        int i = base + j * 256 + tid;
        if (i < nnz) {
            r[j] = row[i]; c[j] = col[i]; v[j] = vals[i];
            b[j] = r[j] >> BSHIFT;
            atomicAdd(&cnt[b[j]], 1);
        } else {
            b[j] = -1;
        }
    }
    __syncthreads();

    // exclusive scan of cnt[0..NBUCK) -> excl[]; 2 bins per thread
    {
        int b0 = 2 * tid, b1 = 2 * tid + 1;
        int c0 = (b0 < NBUCK) ? cnt[b0] : 0;
        int c1 = (b1 < NBUCK) ? cnt[b1] : 0;
        int pair = c0 + c1;
        sm[tid] = pair;
        __syncthreads();
        int incl = pair;
        for (int off = 1; off < 256; off <<= 1) {
            int tv = (tid >= off) ? sm[tid - off] : 0;
            __syncthreads();
            incl += tv;
            sm[tid] = incl;
            __syncthreads();
        }
        int pexcl = incl - pair;
        if (b0 < NBUCK) excl[b0] = pexcl;
        if (b1 < NBUCK) excl[b1] = pexcl + c0;
    }
    __syncthreads();

    // reserve global ranges, then convert cnt[] into LDS cursors
    for (int t = tid; t < NBUCK; t += 256) {
        int cb = cnt[t];
        gbase[t] = (cb > 0) ? atomicAdd(&gfill[t], cb) : 0;
    }
    __syncthreads();
    for (int t = tid; t < NBUCK; t += 256) cnt[t] = excl[t];
    __syncthreads();

    // bin edges into LDS by bucket
#pragma unroll
    for (int j = 0; j < 16; ++j) {
        if (b[j] >= 0) {
            int p = atomicAdd(&cnt[b[j]], 1);
            sstag[p] = make_uint2(((unsigned)(r[j] & 511) << 18) | (unsigned)c[j],
                                  __float_as_uint(v[j]));
            sb[p] = (unsigned short)b[j];
        }
    }
    __syncthreads();

    // write LDS-ordered entries: contiguous global run per bucket
    int tot = nnz - base; if (tot > EPB) tot = EPB;
    for (int i = tid; i < tot; i += 256) {
        int bb = sb[i];
        size_t gp = (size_t)bb * BCAP + gbase[bb] + (i - excl[bb]);
        stag[gp] = sstag[i];
    }
}

// ---------- tiny scan over 391 bucket totals -> bucket CSR bases ----------
__global__ void scanG_k(const int* __restrict__ gfill, int* __restrict__ bbase,
                        int* __restrict__ row_ptr) {
    __shared__ int sm[256];
    int tid = threadIdx.x;
    int j0 = 2 * tid, j1 = 2 * tid + 1;
    int c0 = (j0 < NBUCK) ? gfill[j0] : 0;
    int c1 = (j1 < NBUCK) ? gfill[j1] : 0;
    int pair = c0 + c1;
    sm[tid] = pair;
    __syncthreads();
    int incl = pair;
    for (int off = 1; off < 256; off <<= 1) {
        int t = (tid >= off) ? sm[tid - off] : 0;
        __syncthreads();
        incl += t;
        sm[tid] = incl;
        __syncthreads();
    }
    int pexcl = incl - pair;
    if (j0 < NBUCK) bbase[j0] = pexcl;
    if (j1 < NBUCK) bbase[j1] = pexcl + c0;
    if (tid == 0) row_ptr[N_NODES] = NNZ_E;
}

// ---------- bucket pass B: bucket-local CSR (hist + scan + scatter in LDS) ----------
// One block per bucket. Rows are contiguous per bucket, so global CSR is the
// concatenation of bucket-local CSRs: row_ptr[r] = bbase[b] + lexcl[r&511].
// All atomics are LDS; csr writes land in a 64 KB window (one L2).
// Replaces the 200k-row global histogram + 3-kernel scan entirely.
__global__ __launch_bounds__(256) void bucketB_k(
    const uint2* __restrict__ stag, const int* __restrict__ gfill,
    const int* __restrict__ bbase, int* __restrict__ row_ptr,
    int2* __restrict__ csr) {
    __shared__ int hist[BROWS];     // counts, later cursors
    __shared__ int lexcl[BROWS];
    __shared__ int sm[256];
    int b = blockIdx.x;
    int n = gfill[b];
    int cs = bbase[b];
    const uint2* s = stag + (size_t)b * BCAP;
    int tid = threadIdx.x;

    hist[tid] = 0; hist[tid + 256] = 0;
    __syncthreads();
    for (int i = tid; i < n; i += 256)
        atomicAdd(&hist[s[i].x >> 18], 1);
    __syncthreads();

    // exclusive scan of hist[0..511], 2 rows per thread
    int j0 = 2 * tid, j1 = 2 * tid + 1;
    int c0 = hist[j0], c1 = hist[j1];
    int pair = c0 + c1;
    sm[tid] = pair;
    __syncthreads();
    int incl = pair;
    for (int off = 1; off < 256; off <<= 1) {
        int t = (tid >= off) ? sm[tid - off] : 0;
        __syncthreads();
        incl += t;
        sm[tid] = incl;
        __syncthreads();
    }
    int pexcl = incl - pair;
    lexcl[j0] = pexcl;
    lexcl[j1] = pexcl + c0;

    // emit row_ptr and init cursors (own slots only; sync before cross-use)
    int rbase = b << BSHIFT;
    if (rbase + j0 < N_NODES) row_ptr[rbase + j0] = cs + lexcl[j0];
    if (rbase + j1 < N_NODES) row_ptr[rbase + j1] = cs + lexcl[j1];
    hist[j0] = lexcl[j0];
    hist[j1] = lexcl[j1];
    __syncthreads();

    for (int i = tid; i < n; i += 256) {
        uint2 e = s[i];
        int rl = (int)(e.x >> 18);
        int p = cs + atomicAdd(&hist[rl], 1);
        int2 cv;
        cv.x = (int)(e.x & 0x3FFFF);
        cv.y = (int)e.y;
        csr[p] = cv;
    }
}

// ---------- first fused kernel (per 64-ch group) ----------
// S = spmm(x_g); T1_g = S - x_g (compact);
// out_g = -(w0*x_g + w1*T1_g) + alpha*(x_g - 0.5*S)
// Plain stores (nt reverted: at GRP=64 the hot set ~179 MB fits L3; Round-1
// nt hints converted L3 hits into HBM round-trips, ~+3 us/dispatch).
__global__ __launch_bounds__(256) void first_k(
    const int* __restrict__ rp, const int2* __restrict__ csr,
    const float* __restrict__ x, float* __restrict__ T1g, float* __restrict__ out,
    const float* __restrict__ w, const float* __restrict__ alpha_p, int goff) {
    int wid = blockIdx.x * 4 + (threadIdx.x >> 6);
    int r = __builtin_amdgcn_readfirstlane(wid);
    if (r >= N_NODES) return;
    int lane = threadIdx.x & 63;
    const float* base = x + goff + lane;      // gather x[col*128 + goff + lane]
    int e0 = rp[r], e1 = rp[r + 1];
    float a0 = 0.f, a1 = 0.f, a2 = 0.f, a3 = 0.f;
    int e = e0;
    for (; e + 4 <= e1; e += 4) {
        int2 cv0 = csr[e], cv1 = csr[e + 1], cv2 = csr[e + 2], cv3 = csr[e + 3];
        a0 = fmaf(__int_as_float(cv0.y), base[(size_t)cv0.x * H_CH], a0);
        a1 = fmaf(__int_as_float(cv1.y), base[(size_t)cv1.x * H_CH], a1);
        a2 = fmaf(__int_as_float(cv2.y), base[(size_t)cv2.x * H_CH], a2);
        a3 = fmaf(__int_as_float(cv3.y), base[(size_t)cv3.x * H_CH], a3);
    }
    for (; e < e1; ++e) {
        int2 cv = csr[e];
        a0 = fmaf(__int_as_float(cv.y), base[(size_t)cv.x * H_CH], a0);
    }
    float s = (a0 + a1) + (a2 + a3);
    size_t idxg = (size_t)r * GRP + lane;
    size_t idxf = (size_t)r * H_CH + goff + lane;
    float xr = x[idxf];
    float w0 = w[0], w1 = w[1], al = alpha_p[0];
    float t1 = s - xr;
    float o = -(w0 * xr + w1 * t1) + al * (xr - 0.5f * s);
    T1g[idxg] = t1;
    out[idxf] = o;
}

// ---------- Chebyshev step (per 64-ch group) ----------
// y = spmm(Tcur); Tn = 2*(y - Tcur) - Tprev; out -= w[k]*Tn; Tnext = Tn
__global__ __launch_bounds__(256) void cheb_k(
    const int* __restrict__ rp, const int2* __restrict__ csr,
    const float* __restrict__ Tcur, const float* TprevBase, int tprevStride,
    float* Tnext, float* __restrict__ out,
    const float* __restrict__ w, int k, int goff) {
    int wid = blockIdx.x * 4 + (threadIdx.x >> 6);
    int r = __builtin_amdgcn_readfirstlane(wid);
    if (r >= N_NODES) return;
    int lane = threadIdx.x & 63;
    const float* base = Tcur + lane;          // gather Tcur[col*64 + lane]
    int e0 = rp[r], e1 = rp[r + 1];
    float a0 = 0.f, a1 = 0.f, a2 = 0.f, a3 = 0.f;
    int e = e0;
    for (; e + 4 <= e1; e += 4) {
        int2 cv0 = csr[e], cv1 = csr[e + 1], cv2 = csr[e + 2], cv3 = csr[e + 3];
        a0 = fmaf(__int_as_float(cv0.y), base[(size_t)cv0.x * GRP], a0);
        a1 = fmaf(__int_as_float(cv1.y), base[(size_t)cv1.x * GRP], a1);
        a2 = fmaf(__int_as_float(cv2.y), base[(size_t)cv2.x * GRP], a2);
        a3 = fmaf(__int_as_float(cv3.y), base[(size_t)cv3.x * GRP], a3);
    }
    for (; e < e1; ++e) {
        int2 cv = csr[e];
        a0 = fmaf(__int_as_float(cv.y), base[(size_t)cv.x * GRP], a0);
    }
    float s = (a0 + a1) + (a2 + a3);
    size_t idxg = (size_t)r * GRP + lane;
    size_t idxf = (size_t)r * H_CH + goff + lane;
    float tc = Tcur[idxg];
    float tp = TprevBase[(size_t)r * tprevStride + lane];
    float wk = w[k];
    float tn = 2.0f * (s - tc) - tp;
    float o = out[idxf];
    o -= wk * tn;
    out[idxf] = o;
    Tnext[idxg] = tn;
}

extern "C" void kernel_launch(void* const* d_in, const int* in_sizes, int n_in,
                              void* d_out, int out_size, void* d_ws, size_t ws_size,
                              hipStream_t stream) {
    const float* x      = (const float*)d_in[0];
    const float* vals   = (const float*)d_in[1];
    const float* logits = (const float*)d_in[2];
    const float* alpha  = (const float*)d_in[3];
    const int*   erow   = (const int*)d_in[4];
    const int*   ecol   = (const int*)d_in[5];
    float* out = (float*)d_out;

    const size_t NG = (size_t)N_NODES * GRP;       // per-group state elements
    float* bufA    = (float*)d_ws;                 // N x 64
    float* bufB    = bufA + NG;                    // N x 64
    int2*  csr     = (int2*)(bufB + NG);           // packed col+val, NNZ
    uint2* stag    = (uint2*)(csr + NNZ_E);        // bucket staging, NBUCK*BCAP
    int*   row_ptr = (int*)(stag + (size_t)NBUCK * BCAP);  // N+1
    int*   gfill   = row_ptr + (N_NODES + 1);      // NBUCK
    int*   bbase   = gfill + NBUCK;                // NBUCK
    float* w_buf   = (float*)(bbase + NBUCK);      // 16 entries

    hipMemsetAsync(gfill, 0, NBUCK * sizeof(int), stream);
    softmax_k<<<1, 64, 0, stream>>>(logits, w_buf);

    // bucketed CSR build: bin -> 391-entry scan -> bucket-local CSR
    int nblkA = (NNZ_E + EPB - 1) / EPB;           // 782
    bucketA_k<<<nblkA, 256, 0, stream>>>(erow, ecol, vals, gfill, stag, NNZ_E);
    scanG_k<<<1, 256, 0, stream>>>(gfill, bbase, row_ptr);
    bucketB_k<<<NBUCK, 256, 0, stream>>>(stag, gfill, bbase, row_ptr, csr);

    int grid = (N_NODES + 3) / 4;                  // 4 rows (waves) per 256-thread block

    for (int g = 0; g < H_CH / GRP; ++g) {
        int goff = g * GRP;
        // T1 (compact) -> bufB; out slice initialized
        first_k<<<grid, 256, 0, stream>>>(row_ptr, csr, x, bufB, out, w_buf, alpha, goff);
        // k = 2: Tcur = T1 (bufB), Tprev = x slice (stride 128), Tnext -> bufA
        cheb_k<<<grid, 256, 0, stream>>>(row_ptr, csr, bufB, x + goff, H_CH, bufA,
                                         out, w_buf, 2, goff);
        // k = 3..15: ping-pong; Tnext aliases Tprev (read-before-write per thread)
        float* Tcur = bufA;
        float* Tprev = bufB;
        for (int k = 3; k <= K_DEG; ++k) {
            cheb_k<<<grid, 256, 0, stream>>>(row_ptr, csr, Tcur, Tprev, GRP, Tprev,
                                             out, w_buf, k, goff);
            float* t = Tcur; Tcur = Tprev; Tprev = t;
        }
    }
}